// Round 1
// baseline (655.653 us; speedup 1.0000x reference)
//
#include <hip/hip_runtime.h>
#include <stdint.h>

#define NTOK 16384
#define HD   1024
#define SD   256
#define NE   8

typedef short bf16x8 __attribute__((ext_vector_type(8)));
typedef _Float16 f16x8 __attribute__((ext_vector_type(8)));
typedef float f32x4 __attribute__((ext_vector_type(4)));
typedef unsigned short u16;
typedef unsigned short u16x8 __attribute__((ext_vector_type(8)));

__device__ __forceinline__ u16 f2bf(float f) {
  union { float f; unsigned u; } v; v.f = f;
  return (u16)((v.u + 0x7fffu + ((v.u >> 16) & 1u)) >> 16);
}

__device__ __forceinline__ void gload16(const void* g, void* l) {
  __builtin_amdgcn_global_load_lds((const __attribute__((address_space(1))) void*)g,
                                   (__attribute__((address_space(3))) void*)l,
                                   16, 0, 0);
}

// meta layout (ints): [0..7] counts, [8..15] cursors, [16..24] offsets,
// [25] ntiles(256-row), [32..191] tile_e, [192..351] tile_row0, [352..511] tile_end

// ---------------- Fused prep: aprep (8192 blk) + bprep (64 blk) + tconv (4608 blk) ----------------
__global__ __launch_bounds__(256) void prep_kernel(
    const float* __restrict__ ue, _Float16* __restrict__ aP,
    const float* __restrict__ sw1, _Float16* __restrict__ bP,
    const float* __restrict__ ew1, const float* __restrict__ ew2,
    const float* __restrict__ uw1, const float* __restrict__ uw2,
    u16* __restrict__ ew1t, u16* __restrict__ ew2t,
    u16* __restrict__ uw1t, u16* __restrict__ uw2t) {
  const int bid = blockIdx.x;
  const int tid = threadIdx.x;
  if (bid < 8192) {
    const int t = bid * 256 + tid;
    const int p = t >> 7;
    const int h = (t & 127) << 3;
    const float* s = ue + ((size_t)p << 10) + h;
    const float4 a = *(const float4*)s;
    const float4 b = *(const float4*)(s + 4);
    float v[8] = {a.x, a.y, a.z, a.w, b.x, b.y, b.z, b.w};
    f16x8 hi, lo;
#pragma unroll
    for (int j = 0; j < 8; ++j) {
      const _Float16 h16 = (_Float16)v[j];
      hi[j] = h16;
      lo[j] = (_Float16)(v[j] - (float)h16);
    }
    _Float16* d = aP + ((size_t)p << 11) + h;
    *(f16x8*)d = hi;
    *(f16x8*)(d + 1024) = lo;
    return;
  }
  __shared__ float tb[64][65];
  if (bid < 8256) {
    const int b = bid - 8192;
    const int c0 = (b & 3) << 6;
    const int r0 = (b >> 2) << 6;
    {
      const int lr = tid >> 2, q = (tid & 3) << 4;
      const float* s = sw1 + (size_t)(r0 + lr) * SD + c0 + q;
#pragma unroll
      for (int j = 0; j < 16; j += 4) {
        const float4 v = *(const float4*)(s + j);
        tb[lr][q + j] = v.x; tb[lr][q + j + 1] = v.y;
        tb[lr][q + j + 2] = v.z; tb[lr][q + j + 3] = v.w;
      }
    }
    __syncthreads();
    const int lc = tid >> 2, rq = (tid & 3) << 4;
    f16x8 hi0, hi1, lo0, lo1;
#pragma unroll
    for (int j = 0; j < 8; ++j) {
      const float v0 = tb[rq + j][lc];
      const _Float16 h0 = (_Float16)v0;
      hi0[j] = h0; lo0[j] = (_Float16)(v0 - (float)h0);
      const float v1 = tb[rq + 8 + j][lc];
      const _Float16 h1 = (_Float16)v1;
      hi1[j] = h1; lo1[j] = (_Float16)(v1 - (float)h1);
    }
    _Float16* d = bP + (size_t)(c0 + lc) * 3072 + r0 + rq;
    *(f16x8*)d = hi0;           *(f16x8*)(d + 8) = hi1;
    *(f16x8*)(d + 1024) = lo0;  *(f16x8*)(d + 1032) = lo1;
    *(f16x8*)(d + 2048) = hi0;  *(f16x8*)(d + 2056) = hi1;
    return;
  }
  const int c = bid - 8256;
  const int m = c >> 8;
  const int t2 = c & 255;
  const int c0 = (t2 & 15) << 6;
  const int r0 = (t2 >> 4) << 6;
  const size_t msz = (size_t)HD * HD;
  const float* src; u16* dst;
  if (m < 8)       { src = ew1 + (size_t)m * msz;       dst = ew1t + (size_t)m * msz; }
  else if (m < 16) { src = ew2 + (size_t)(m - 8) * msz; dst = ew2t + (size_t)(m - 8) * msz; }
  else if (m == 16){ src = uw1;                          dst = uw1t; }
  else             { src = uw2;                          dst = uw2t; }
  {
    const int lr = tid >> 2, q = (tid & 3) << 4;
    const float* s = src + (size_t)(r0 + lr) * HD + c0 + q;
#pragma unroll
    for (int j = 0; j < 16; j += 4) {
      const float4 v = *(const float4*)(s + j);
      tb[lr][q + j] = v.x; tb[lr][q + j + 1] = v.y;
      tb[lr][q + j + 2] = v.z; tb[lr][q + j + 3] = v.w;
    }
  }
  __syncthreads();
  {
    const int lc = tid >> 2, rq = (tid & 3) << 4;
    u16x8 o0, o1;
#pragma unroll
    for (int j = 0; j < 8; ++j) o0[j] = f2bf(tb[rq + j][lc]);
#pragma unroll
    for (int j = 0; j < 8; ++j) o1[j] = f2bf(tb[rq + 8 + j][lc]);
    u16* d = dst + (size_t)(c0 + lc) * HD + r0 + rq;
    *(u16x8*)d = o0;
    *(u16x8*)(d + 8) = o1;
  }
}

// ---------------- Router GEMM: hidden[p][s] = relu(3-term hi/lo fp16 MFMA + sb1), f32 out ----------------
__global__ __launch_bounds__(256) void rgemm_kernel(
    const _Float16* __restrict__ aP, const _Float16* __restrict__ bP,
    const float* __restrict__ sb1, float* __restrict__ hidden) {
  const int p = blockIdx.x;
  const int L = (p & 7) * 64 + (p >> 3);
  const int jt = L & 3;
  const int row0 = (L >> 2) << 7;

  __shared__ _Float16 sA[2][128 * 32];
  __shared__ _Float16 sB[2][64 * 32];

  const int tid = threadIdx.x, lane = tid & 63, wave = tid >> 6;
  const int wr = (wave >> 1) << 6, wc = (wave & 1) << 5;
  const int smrow = tid >> 2, skoff = (tid & 3) << 3;
  const _Float16* ar0 = aP + ((size_t)(row0 + smrow) << 11) + skoff;
  const _Float16* ar1 = aP + ((size_t)(row0 + smrow + 64) << 11) + skoff;
  const _Float16* br  = bP + (size_t)((jt << 6) + smrow) * 3072 + skoff;
  const int ldsoff = wave << 10;

  f32x4 acc[4][2];
#pragma unroll
  for (int i = 0; i < 4; ++i)
#pragma unroll
    for (int j = 0; j < 2; ++j) acc[i][j] = (f32x4){0.f, 0.f, 0.f, 0.f};

  gload16(ar0, (char*)sA[0] + ldsoff);
  gload16(ar1, (char*)sA[0] + 4096 + ldsoff);
  gload16(br,  (char*)sB[0] + ldsoff);

  const int afrag = (wr + (lane & 15)) * 32 + ((lane >> 4) << 3);
  const int bfrag = (wc + (lane & 15)) * 32 + ((lane >> 4) << 3);

  for (int ks = 0; ks < 96; ++ks) {
    const int buf = ks & 1;
    __syncthreads();
    if (ks + 1 < 96) {
      const int k1 = ks + 1;
      const int pa = (k1 < 64) ? ((k1 & 31) << 5) : (1024 + ((k1 - 64) << 5));
      gload16(ar0 + pa, (char*)sA[buf ^ 1] + ldsoff);
      gload16(ar1 + pa, (char*)sA[buf ^ 1] + 4096 + ldsoff);
      gload16(br + (k1 << 5), (char*)sB[buf ^ 1] + ldsoff);
    }
    f16x8 av[4], bv[2];
#pragma unroll
    for (int f = 0; f < 4; ++f) av[f] = *(const f16x8*)&sA[buf][afrag + f * 512];
#pragma unroll
    for (int f = 0; f < 2; ++f) bv[f] = *(const f16x8*)&sB[buf][bfrag + f * 512];
#pragma unroll
    for (int i = 0; i < 4; ++i)
#pragma unroll
      for (int j = 0; j < 2; ++j)
        acc[i][j] = __builtin_amdgcn_mfma_f32_16x16x32_f16(av[i], bv[j], acc[i][j], 0, 0, 0);
  }

  const int lc = lane & 15, lr4 = (lane >> 4) << 2;
#pragma unroll
  for (int j = 0; j < 2; ++j) {
    const int c = (jt << 6) + wc + (j << 4) + lc;
    const float bias = sb1[c];
#pragma unroll
    for (int i = 0; i < 4; ++i) {
      const int rl = wr + (i << 4) + lr4;
#pragma unroll
      for (int q = 0; q < 4; ++q)
        hidden[((size_t)(row0 + rl + q) << 8) + c] = fmaxf(acc[i][j][q] + bias, 0.f);
    }
  }
}

// ---------------- Logits layer-2 (f32, fixed order) + argmax + histogram ----------------
__global__ __launch_bounds__(256) void logits_kernel(
    const float* __restrict__ hidden, const float* __restrict__ sw2,
    const float* __restrict__ sb2, int* __restrict__ routes, int* meta) {
  __shared__ float logl[32][8];
  const int tid = threadIdx.x;
  const int tok0 = blockIdx.x << 5;
  const int tl = tid >> 3, e2 = tid & 7;
  const float* hp = hidden + ((size_t)(tok0 + tl) << 8);
  float a0 = 0.f, a1 = 0.f, a2 = 0.f, a3 = 0.f;
  for (int q = 0; q < SD; q += 8) {
    const float4 h0 = *(const float4*)&hp[q];
    const float4 h1 = *(const float4*)&hp[q + 4];
    a0 = fmaf(h0.x, sw2[((q + 0) << 3) + e2], a0);
    a1 = fmaf(h0.y, sw2[((q + 1) << 3) + e2], a1);
    a2 = fmaf(h0.z, sw2[((q + 2) << 3) + e2], a2);
    a3 = fmaf(h0.w, sw2[((q + 3) << 3) + e2], a3);
    a0 = fmaf(h1.x, sw2[((q + 4) << 3) + e2], a0);
    a1 = fmaf(h1.y, sw2[((q + 5) << 3) + e2], a1);
    a2 = fmaf(h1.z, sw2[((q + 6) << 3) + e2], a2);
    a3 = fmaf(h1.w, sw2[((q + 7) << 3) + e2], a3);
  }
  logl[tl][e2] = (a0 + a1) + (a2 + a3) + sb2[e2];
  __syncthreads();
  if (tid < 32) {
    float best = logl[tid][0]; int be = 0;
#pragma unroll
    for (int e = 1; e < 8; ++e) {
      const float v = logl[tid][e];
      if (v > best) { best = v; be = e; }
    }
    routes[tok0 + tid] = be;
    atomicAdd(&meta[be], 1);
  }
}

// ---------------- Scan: offsets + 256-row tile table ----------------
__global__ void scan_kernel(int* meta) {
  if (threadIdx.x != 0) return;
  int off = 0;
  for (int e = 0; e < NE; ++e) { meta[16 + e] = off; off += meta[e]; }
  meta[24] = off;
  int nt = 0;
  for (int e = 0; e < NE; ++e) {
    const int s = meta[16 + e], en = meta[16 + e + 1];
    for (int r0 = s; r0 < en; r0 += 256) {
      meta[32 + nt] = e; meta[192 + nt] = r0; meta[352 + nt] = en; ++nt;
    }
  }
  meta[25] = nt;
}

// ---------------- Build permutation (token -> grouped position) ----------------
__global__ void perm_kernel(const int* __restrict__ routes, int* meta, int* __restrict__ perm) {
  const int b = blockIdx.x * 256 + threadIdx.x;
  const int r = routes[b];
  const int pos = meta[16 + r] + atomicAdd(&meta[8 + r], 1);
  perm[pos] = b;
}

// ---------------- Gather x rows into grouped order, f32 -> bf16 ----------------
__global__ __launch_bounds__(256) void gatherx_kernel(
    const float* __restrict__ x, const int* __restrict__ perm, u16* __restrict__ xg) {
  const int t = blockIdx.x * 256 + threadIdx.x;
  const int p = t >> 7;
  const int j = (t & 127) << 3;
  const int tok = perm[p];
  const float* s = &x[((size_t)tok << 10) + j];
  const float4 a = *(const float4*)s;
  const float4 b = *(const float4*)(s + 4);
  u16x8 o;
  o[0] = f2bf(a.x); o[1] = f2bf(a.y); o[2] = f2bf(a.z); o[3] = f2bf(a.w);
  o[4] = f2bf(b.x); o[5] = f2bf(b.y); o[6] = f2bf(b.z); o[7] = f2bf(b.w);
  *(u16x8*)&xg[((size_t)p << 10) + j] = o;
}

// ================= Phase-split pipelined GEMMs =================
// BM=256, BN=128, BK=64, 512 threads = 8 waves (2 row x 4 col).
// LDS: A 2x[256 slots][64], B 2x[128 slots][64], XOR-swizzled k within each
// row: k_u16 ^= (slot&7)<<3 (applied on pre-swizzled global SOURCE for
// global_load_lds + on every ds_read -- both-sides rule).
// A slot bands permuted [0,2,1,3] so LDS half h == rows read in phase rh=h.
// Schedule per iter (2 K-tiles, buf0=even tile, buf1=odd):
//   P1: rd A0h0+B0, stg t(2i+1).Ah1->b1 | P2: rd A0h1, stg t(2i+2).{Ah0,B}->b0, vmcnt(4)
//   P3: rd A1h0+B1, stg t(2i+2).Ah1->b0 | P4: rd A1h1, stg t(2i+3).{Ah0,B}->b1, vmcnt(4)
// Counted vmcnt(4) = 2 stage-units in flight; never drains to 0 in main loop.

#define BAR __builtin_amdgcn_s_barrier()
#define LGKM0 do { asm volatile("s_waitcnt lgkmcnt(0)" ::: "memory"); \
                   __builtin_amdgcn_sched_barrier(0); } while (0)
#define VMC(N) asm volatile("s_waitcnt vmcnt(" #N ")" ::: "memory")
#define PRI1 __builtin_amdgcn_s_setprio(1)
#define PRI0 do { __builtin_amdgcn_s_setprio(0); __builtin_amdgcn_sched_barrier(0); } while (0)

#define RD_A(B, RH) do { _Pragma("unroll") \
  for (int f_ = 0; f_ < 4; ++f_) { \
    av[f_ * 2 + 0] = *(const bf16x8*)&As[B][(RH) * 8192 + aRd + f_ * 1024 + k0]; \
    av[f_ * 2 + 1] = *(const bf16x8*)&As[B][(RH) * 8192 + aRd + f_ * 1024 + k1]; } } while (0)

#define RD_B(B) do { _Pragma("unroll") \
  for (int g_ = 0; g_ < 2; ++g_) { \
    bv[g_ * 2 + 0] = *(const bf16x8*)&Bs[B][bRd + g_ * 1024 + k0]; \
    bv[g_ * 2 + 1] = *(const bf16x8*)&Bs[B][bRd + g_ * 1024 + k1]; } } while (0)

#define MM(RH) do { _Pragma("unroll") \
  for (int f_ = 0; f_ < 4; ++f_) { _Pragma("unroll") \
    for (int g_ = 0; g_ < 2; ++g_) { \
      acc[(RH) * 4 + f_][g_] = __builtin_amdgcn_mfma_f32_16x16x32_bf16( \
          av[f_ * 2 + 0], bv[g_ * 2 + 0], acc[(RH) * 4 + f_][g_], 0, 0, 0); \
      acc[(RH) * 4 + f_][g_] = __builtin_amdgcn_mfma_f32_16x16x32_bf16( \
          av[f_ * 2 + 1], bv[g_ * 2 + 1], acc[(RH) * 4 + f_][g_], 0, 0, 0); } } } while (0)

// ---------------- GEMM1: hid[p][0:2048] = relu(xg[p] @ [ew1[e] | uw1] + bias) ----------------
__global__ __launch_bounds__(512, 2) void gemm1_kernel(
    const u16* __restrict__ xg, const u16* __restrict__ ew1t,
    const u16* __restrict__ uw1t, const float* __restrict__ eb1,
    const float* __restrict__ ub1, const int* __restrict__ meta,
    u16* __restrict__ hid) {
  const int nt = meta[25];
  const int pb = blockIdx.x;                 // grid 1152 = 8 * 144
  const int L = (pb & 7) * 144 + (pb >> 3);  // bijective XCD swizzle
  const int mt = L >> 4;
  const int jt = L & 15;
  if (mt >= nt) return;
  const int e = meta[32 + mt], row0 = meta[192 + mt], gend = meta[352 + mt];
  const u16* wbase = (jt < 8)
      ? ew1t + ((size_t)e << 20) + ((size_t)(jt << 7) << 10)
      : uw1t + ((size_t)((jt - 8) << 7) << 10);

  __shared__ u16 As[2][256 * 64];
  __shared__ u16 Bs[2][128 * 64];

  const int tid = threadIdx.x, lane = tid & 63, w = tid >> 6;
  const int wm = w >> 2, wn = w & 3;
  const int l15 = lane & 15, kl = lane >> 4;
  const int lo3 = lane >> 3, cc = lane & 7;
  const int ku = (cc ^ lo3) << 3;     // pre-swizzled global k offset

  // staging offsets (u16 units); add t*64 at stage time
  int aoff[2][2];
#pragma unroll
  for (int h = 0; h < 2; ++h)
#pragma unroll
    for (int l = 0; l < 2; ++l) {
      const int s = h * 128 + (w * 2 + l) * 8 + lo3;
      const int band = s >> 6;
      int r = row0 + ((((band & 1) << 1) | (band >> 1)) << 6) + (s & 63);
      if (r > NTOK - 1) r = NTOK - 1;   // clamp: OOB rows read valid junk, masked at store
      aoff[h][l] = (r << 10) + ku;
    }
  int boff[2];
#pragma unroll
  for (int l = 0; l < 2; ++l) {
    const int s = (w * 2 + l) * 8 + lo3;
    boff[l] = (s << 10) + ku;
  }
  const int aDst[2] = { (w * 2 + 0) * 512, (w * 2 + 1) * 512 };

#define STG_A1(B, T, H) do { \
  gload16(xg + aoff[H][0] + ((T) << 6), (u16*)&As[B][(H) * 8192 + aDst[0]]); \
  gload16(xg + aoff[H][1] + ((T) << 6), (u16*)&As[B][(H) * 8192 + aDst[1]]); } while (0)
#define STG_B1(B, T) do { \
  gload16(wbase + boff[0] + ((T) << 6), (u16*)&Bs[B][aDst[0]]); \
  gload16(wbase + boff[1] + ((T) << 6), (u16*)&Bs[B][aDst[1]]); } while (0)

  // read offsets (swizzled)
  const int k0 = (kl ^ cc) << 3;
  const int k1 = ((4 + kl) ^ cc) << 3;
  const int aRd = wm * 4096 + l15 * 64;
  const int bRd = wn * 2048 + l15 * 64;

  f32x4 acc[8][2];
#pragma unroll
  for (int i = 0; i < 8; ++i)
#pragma unroll
    for (int j = 0; j < 2; ++j) acc[i][j] = (f32x4){0.f, 0.f, 0.f, 0.f};
  bf16x8 av[8], bv[4];

  // prologue: t0 {Ah0, B, Ah1} -> buf0 ; t1 {Ah0, B} -> buf1
  STG_A1(0, 0, 0); STG_B1(0, 0); STG_A1(0, 0, 1);
  STG_A1(1, 1, 0); STG_B1(1, 1);
  VMC(4);   // t0 fully landed; t1 in flight
  BAR;

  for (int i = 0; i < 7; ++i) {   // K=1024 -> NT=16, NI=8
    const int t1 = 2 * i + 1, t2 = 2 * i + 2, t3 = 2 * i + 3;
    RD_A(0, 0); RD_B(0);
    STG_A1(1, t1, 1);
    BAR; LGKM0; PRI1; MM(0); PRI0; BAR;
    RD_A(0, 1);
    STG_A1(0, t2, 0); STG_B1(0, t2);
    BAR; LGKM0; VMC(4); PRI1; MM(1); PRI0; BAR;
    RD_A(1, 0); RD_B(1);
    STG_A1(0, t2, 1);
    BAR; LGKM0; PRI1; MM(0); PRI0; BAR;
    RD_A(1, 1);
    STG_A1(1, t3, 0); STG_B1(1, t3);
    BAR; LGKM0; VMC(4); PRI1; MM(1); PRI0; BAR;
  }
  // epilogue: tiles 14 (buf0), 15 (buf1)
  RD_A(0, 0); RD_B(0);
  STG_A1(1, 15, 1);
  BAR; LGKM0; PRI1; MM(0); PRI0; BAR;
  RD_A(0, 1);
  BAR; LGKM0; VMC(0); PRI1; MM(1); PRI0; BAR;
  RD_A(1, 0); RD_B(1);
  BAR; LGKM0; PRI1; MM(0); PRI0; BAR;
  RD_A(1, 1);
  BAR; LGKM0; PRI1; MM(1); PRI0; BAR;

  const int cb = (jt << 7) + (wn << 5);
#pragma unroll
  for (int g = 0; g < 2; ++g) {
    const int c = cb + g * 16 + l15;
    const float bias = (c < 1024) ? eb1[(e << 10) + c] : ub1[c - 1024];
#pragma unroll
    for (int rf = 0; rf < 8; ++rf) {
      const int rr = row0 + (wm << 7) + rf * 16 + (kl << 2);
#pragma unroll
      for (int q = 0; q < 4; ++q)
        if (rr + q < gend)
          hid[((size_t)(rr + q) << 11) + c] = f2bf(fmaxf(acc[rf][g][q] + bias, 0.f));
    }
  }
#undef STG_A1
#undef STG_B1
}

// ---------------- GEMM2: out[perm[p]][c] = hid[p] @ [ew2[e]; uw2] + eb2[e] + ub2 ----------------
__global__ __launch_bounds__(512, 2) void gemm2_kernel(
    const u16* __restrict__ hid, const u16* __restrict__ ew2t,
    const u16* __restrict__ uw2t, const float* __restrict__ eb2,
    const float* __restrict__ ub2, const int* __restrict__ meta,
    const int* __restrict__ perm, float* __restrict__ out) {
  const int nt = meta[25];
  const int pb = blockIdx.x;                // grid 576 = 8 * 72
  const int L = (pb & 7) * 72 + (pb >> 3);
  const int mt = L >> 3;
  const int jt = L & 7;
  if (mt >= nt) return;
  const int e = meta[32 + mt], row0 = meta[192 + mt], gend = meta[352 + mt];
  const u16* ebase = ew2t + ((size_t)e << 20);
  const int n0 = jt << 7;

  __shared__ u16 As[2][256 * 64];
  __shared__ u16 Bs[2][128 * 64];

  const int tid = threadIdx.x, lane = tid & 63, w = tid >> 6;
  const int wm = w >> 2, wn = w & 3;
  const int l15 = lane & 15, kl = lane >> 4;
  const int lo3 = lane >> 3, cc = lane & 7;
  const int ku = (cc ^ lo3) << 3;

  int aoff[2][2];
#pragma unroll
  for (int h = 0; h < 2; ++h)
#pragma unroll
    for (int l = 0; l < 2; ++l) {
      const int s = h * 128 + (w * 2 + l) * 8 + lo3;
      const int band = s >> 6;
      int r = row0 + ((((band & 1) << 1) | (band >> 1)) << 6) + (s & 63);
      if (r > NTOK - 1) r = NTOK - 1;
      aoff[h][l] = (r << 11) + ku;          // hid stride 2048
    }
  int boff[2];
#pragma unroll
  for (int l = 0; l < 2; ++l) {
    const int s = (w * 2 + l) * 8 + lo3;
    boff[l] = ((n0 + s) << 10) + ku;
  }
  const int aDst[2] = { (w * 2 + 0) * 512, (w * 2 + 1) * 512 };

#define STG_A2(B, T, H) do { \
  gload16(hid + aoff[H][0] + ((T) << 6), (u16*)&As[B][(H) * 8192 + aDst[0]]); \
  gload16(hid + aoff[H][1] + ((T) << 6), (u16*)&As[B][(H) * 8192 + aDst[1]]); } while (0)
#define STG_B2(B, T) do { \
  const u16* wb_ = ((T) < 16) ? ebase : uw2t; const int kk_ = ((T) & 15) << 6; \
  gload16(wb_ + boff[0] + kk_, (u16*)&Bs[B][aDst[0]]); \
  gload16(wb_ + boff[1] + kk_, (u16*)&Bs[B][aDst[1]]); } while (0)

  const int k0 = (kl ^ cc) << 3;
  const int k1 = ((4 + kl) ^ cc) << 3;
  const int aRd = wm * 4096 + l15 * 64;
  const int bRd = wn * 2048 + l15 * 64;

  f32x4 acc[8][2];
#pragma unroll
  for (int i = 0; i < 8; ++i)
#pragma unroll
    for (int j = 0; j < 2; ++j) acc[i][j] = (f32x4){0.f, 0.f, 0.f, 0.f};
  bf16x8 av[8], bv[4];

  STG_A2(0, 0, 0); STG_B2(0, 0); STG_A2(0, 0, 1);
  STG_A2(1, 1, 0); STG_B2(1, 1);
  VMC(4);
  BAR;

  for (int i = 0; i < 15; ++i) {   // K=2048 -> NT=32, NI=16
    const int t1 = 2 * i + 1, t2 = 2 * i + 2, t3 = 2 * i + 3;
    RD_A(0, 0); RD_B(0);
    STG_A2(1, t1, 1);
    BAR; LGKM0; PRI1; MM(0); PRI0; BAR;
    RD_A(0, 1);
    STG_A2(0, t2, 0); STG_B2(0, t2);
    BAR; LGKM0; VMC(4); PRI1; MM(1); PRI0; BAR;
    RD_A(1, 0); RD_B(1);
    STG_A2(0, t2, 1);
    BAR; LGKM0; PRI1; MM(0); PRI0; BAR;
    RD_A(1, 1);
    STG_A2(1, t3, 0); STG_B2(1, t3);
    BAR; LGKM0; VMC(4); PRI1; MM(1); PRI0; BAR;
  }
  // epilogue: tiles 30 (buf0), 31 (buf1)
  RD_A(0, 0); RD_B(0);
  STG_A2(1, 31, 1);
  BAR; LGKM0; PRI1; MM(0); PRI0; BAR;
  RD_A(0, 1);
  BAR; LGKM0; VMC(0); PRI1; MM(1); PRI0; BAR;
  RD_A(1, 0); RD_B(1);
  BAR; LGKM0; PRI1; MM(0); PRI0; BAR;
  RD_A(1, 1);
  BAR; LGKM0; PRI1; MM(1); PRI0; BAR;

  const int cb = (jt << 7) + (wn << 5);
  float b2[2];
#pragma unroll
  for (int g = 0; g < 2; ++g) {
    const int c = cb + g * 16 + l15;
    b2[g] = eb2[(e << 10) + c] + ub2[c];
  }
#pragma unroll
  for (int rf = 0; rf < 8; ++rf) {
#pragma unroll
    for (int q = 0; q < 4; ++q) {
      const int p = row0 + (wm << 7) + rf * 16 + (kl << 2) + q;
      if (p < gend) {
        float* orow = out + ((size_t)perm[p] << 10);
        orow[cb + l15]      = acc[rf][0][q] + b2[0];
        orow[cb + 16 + l15] = acc[rf][1][q] + b2[1];
      }
    }
  }
#undef STG_A2
#undef STG_B2
}

extern "C" void kernel_launch(void* const* d_in, const int* in_sizes, int n_in,
                              void* d_out, int out_size, void* d_ws, size_t ws_size,
                              hipStream_t stream) {
  const float* x   = (const float*)d_in[0];
  const float* ue  = (const float*)d_in[1];
  const float* sw1 = (const float*)d_in[2];
  const float* sb1 = (const float*)d_in[3];
  const float* sw2 = (const float*)d_in[4];
  const float* sb2 = (const float*)d_in[5];
  const float* ew1 = (const float*)d_in[6];
  const float* eb1 = (const float*)d_in[7];
  const float* ew2 = (const float*)d_in[8];
  const float* eb2 = (const float*)d_in[9];
  const float* uw1 = (const float*)d_in[10];
  const float* ub1 = (const float*)d_in[11];
  const float* uw2 = (const float*)d_in[12];
  const float* ub2 = (const float*)d_in[13];
  float* out = (float*)d_out;

  char* w = (char*)d_ws;
  int* meta = (int*)w;    w += 4096;
  int* routes = (int*)w;  w += NTOK * 4;
  int* perm = (int*)w;    w += NTOK * 4;
  char* region = w;
  u16* xg   = (u16*)region;                                             // 33,816,576 B (incl 128-row pad)
  u16* ew1t = (u16*)(region + 33816576ull);                             // 16 MiB
  u16* ew2t = (u16*)(region + 33816576ull + 16777216ull);               // 16 MiB
  u16* uw1t = (u16*)(region + 33816576ull + 2 * 16777216ull);           // 2 MiB
  u16* uw2t = (u16*)(region + 33816576ull + 2 * 16777216ull + 2097152ull);
  u16* hid  = (u16*)(region + 33816576ull + 2 * 16777216ull + 2 * 2097152ull);  // 67,633,152 B
  const size_t region_sz = 33816576ull + 2 * 16777216ull + 2 * 2097152ull + 67633152ull;
  // router-phase aliases live in the (dead-until-gemm1) hid region / xg region:
  _Float16* aP     = (_Float16*)(region + 33816576ull + 2 * 16777216ull + 2 * 2097152ull);
  float* hidden32  = (float*)region;
  _Float16* bP     = (_Float16*)(region + 16777216ull);
  if (135168ull + region_sz > ws_size) return;

  hipMemsetAsync(meta, 0, 4096, stream);
  prep_kernel<<<12864, 256, 0, stream>>>(ue, aP, sw1, bP, ew1, ew2, uw1, uw2,
                                         ew1t, ew2t, uw1t, uw2t);
  rgemm_kernel<<<512, 256, 0, stream>>>(aP, bP, sb1, hidden32);
  logits_kernel<<<NTOK / 32, 256, 0, stream>>>(hidden32, sw2, sb2, routes, meta);
  scan_kernel<<<1, 64, 0, stream>>>(meta);
  perm_kernel<<<NTOK / 256, 256, 0, stream>>>(routes, meta, perm);
  gatherx_kernel<<<(NTOK * 128) / 256, 256, 0, stream>>>(x, perm, xg);
  gemm1_kernel<<<1152, 512, 0, stream>>>(xg, ew1t, uw1t, eb1, ub1, meta, hid);
  gemm2_kernel<<<576, 512, 0, stream>>>(hid, ew2t, uw2t, eb2, ub2, meta, perm, out);
}